// Round 9
// baseline (112.514 us; speedup 1.0000x reference)
//
#include <hip/hip_runtime.h>

#define NPG 148      // nodes per graph
#define EPG 592      // edges per graph
#define NTHR 256
#define SAC 168      // Ahat col stride (f16): 84 dwords -> 2-way max bank alias on frag reads
#define SHT 168      // H^T col stride (f16)
#define SA  36       // AGG row stride (f16)
#define SW  40       // Wt row stride (f16)
#define MTT 10       // m-tiles (148 -> 160)

typedef _Float16 h8 __attribute__((ext_vector_type(8)));
typedef _Float16 h4 __attribute__((ext_vector_type(4)));
typedef float    f4 __attribute__((ext_vector_type(4)));

__device__ __forceinline__ float f16b(unsigned short u) {
    return (float)__builtin_bit_cast(_Float16, u);
}
__device__ __forceinline__ h8 h8zero() {
    h8 z;
    #pragma unroll
    for (int u = 0; u < 8; ++u) z[u] = (_Float16)0;
    return z;
}

// f16 atomic add into LDS via u32 CAS (duplicate edges are rare -> retries ~never)
__device__ __forceinline__ void cas_add_f16(unsigned int* cell, int half, float val) {
    unsigned int old = *(volatile unsigned int*)cell;
    while (true) {
        const unsigned short h = (unsigned short)(old >> (half * 16));
        const unsigned short nh =
            __builtin_bit_cast(unsigned short, (_Float16)(f16b(h) + val));
        const unsigned int nw = half ? ((old & 0x0000ffffu) | ((unsigned)nh << 16))
                                     : ((old & 0xffff0000u) | nh);
        const unsigned int got = atomicCAS(cell, old, nw);
        if (got == old) break;
        old = got;
    }
}

// One block = one graph. Dense-adjacency formulation:
//   Ahat[d][s] = mult(s,d)*dis[s]  (+ dis[d] on diagonal), f16, layer-invariant
//   AGG = Ahat @ H      (MFMA over K=160 node dim; H read via H^T for contiguous B-frags)
//   H'  = relu(dis_d * (AGG @ W) + b)  (MFMA; dis_d folded into epilogue; H'^T written back)
// MFMA layouts (verified r4-r7): A lane(l16=m,q=kchunk) 8 contig k; B lane(l16=n,q=kchunk)
// 8 contig k; D col=l16, row=q*4+rr.

template<int NT_AGG, int NT_W, int WROW, int BOFF, bool LAST>
__device__ __forceinline__ void layer(int t,
    const _Float16* __restrict__ Ahat, _Float16* __restrict__ HT,
    _Float16* __restrict__ AGG, const _Float16* __restrict__ Wt,
    const _Float16* __restrict__ s_bh, const unsigned short* __restrict__ dis16,
    float* __restrict__ gout)
{
    const int w   = t >> 6;
    const int l16 = t & 15;
    const int q   = (t >> 4) & 3;

    // ---- AGG = Ahat @ H : hoist B-frags (shared over j), then per-mt A-frags ----
    h8 bf[NT_AGG][5];
    #pragma unroll
    for (int nt = 0; nt < NT_AGG; ++nt)
        #pragma unroll
        for (int kt = 0; kt < 5; ++kt)
            bf[nt][kt] = *reinterpret_cast<const h8*>(&HT[(nt * 16 + l16) * SHT + kt * 32 + q * 8]);

    #pragma unroll
    for (int j = 0; j < 3; ++j) {
        const int mt = w + 4 * j;
        if (mt < MTT) {
            const int node = mt * 16 + l16;
            h8 af[5];
            #pragma unroll
            for (int kt = 0; kt < 5; ++kt)
                af[kt] = (node < NPG)
                    ? *reinterpret_cast<const h8*>(&Ahat[node * SAC + kt * 32 + q * 8])
                    : h8zero();
            #pragma unroll
            for (int nt = 0; nt < NT_AGG; ++nt) {
                f4 acc = {0.f, 0.f, 0.f, 0.f};
                #pragma unroll
                for (int kt = 0; kt < 5; ++kt)
                    acc = __builtin_amdgcn_mfma_f32_16x16x32_f16(af[kt], bf[nt][kt], acc, 0, 0, 0);
                const int col = nt * 16 + l16;
                #pragma unroll
                for (int rr = 0; rr < 4; ++rr) {
                    const int row = mt * 16 + q * 4 + rr;
                    if (row < NPG) AGG[row * SA + col] = (_Float16)acc[rr];
                }
            }
        }
    }
    __syncthreads();

    // ---- H' = relu(dis_d * (AGG @ W) + b) ----
    #pragma unroll
    for (int j = 0; j < 3; ++j) {
        const int mt = w + 4 * j;
        if (mt < MTT) {
            const int node = mt * 16 + l16;
            const h8 af = (node < NPG)
                ? *reinterpret_cast<const h8*>(&AGG[node * SA + q * 8])
                : h8zero();
            const int r0 = mt * 16 + q * 4;
            float dsc[4];
            #pragma unroll
            for (int rr = 0; rr < 4; ++rr)
                dsc[rr] = (r0 + rr < NPG) ? f16b(dis16[r0 + rr]) : 0.f;
            #pragma unroll
            for (int nt = 0; nt < NT_W; ++nt) {
                const h8 bfw = *reinterpret_cast<const h8*>(&Wt[(WROW + nt * 16 + l16) * SW + q * 8]);
                f4 acc = {0.f, 0.f, 0.f, 0.f};
                acc = __builtin_amdgcn_mfma_f32_16x16x32_f16(af, bfw, acc, 0, 0, 0);
                const int col = nt * 16 + l16;
                const float bias = (float)s_bh[BOFF + col];
                if (LAST) {
                    #pragma unroll
                    for (int rr = 0; rr < 4; ++rr) {
                        const int row = r0 + rr;
                        if (row < NPG)
                            gout[row * 64 + col] = fmaxf(fmaf(acc[rr], dsc[rr], bias), 0.f);
                    }
                } else {
                    if (r0 < NPG) {          // 148%4==0: h4 window fully in or fully out
                        h4 v;
                        #pragma unroll
                        for (int rr = 0; rr < 4; ++rr)
                            v[rr] = (_Float16)fmaxf(fmaf(acc[rr], dsc[rr], bias), 0.f);
                        *reinterpret_cast<h4*>(&HT[col * SHT + r0]) = v;
                    }
                }
            }
        }
    }
    if (!LAST) __syncthreads();
}

__global__ __launch_bounds__(256, 2)
void gcn_fused(const float* __restrict__ x,
               const int* __restrict__ esrc, const int* __restrict__ edst,
               const float* __restrict__ W1, const float* __restrict__ b1,
               const float* __restrict__ W2, const float* __restrict__ b2,
               const float* __restrict__ W3, const float* __restrict__ b3,
               float* __restrict__ out)
{
    __shared__ __align__(16) _Float16 Ahat[NPG * SAC];   // 49,728 B dense normalized adjacency
    __shared__ __align__(16) _Float16 HT[32 * SHT];      // 10,752 B H^T (feat-major)
    __shared__ __align__(16) _Float16 AGG[NPG * SA];     // 10,656 B row-major AGG
    __shared__ __align__(16) _Float16 Wt[112 * SW];      //  8,960 B W1t|W2t|W3t (K-padded)
    __shared__ __align__(16) _Float16 s_bh[112];
    __shared__ __align__(16) unsigned short dis16[160];
    __shared__ int s_cnt[NPG];
    // total ~81.3 KB -> 2 blocks/CU (limit 81,920 B at 2/CU)

    const int t  = threadIdx.x;
    const int g  = blockIdx.x;
    const int be = g * EPG;
    const int bn = g * NPG;

    // ---- P0a: zero ALL f16 staging buffers (incl. Wt K-pad cols! r8 bug) + counters ----
    for (int i = t; i < NPG * SAC / 8; i += NTHR) reinterpret_cast<f4*>(Ahat)[i] = f4{0.f, 0.f, 0.f, 0.f};
    for (int i = t; i < 32 * SHT / 8;  i += NTHR) reinterpret_cast<f4*>(HT)[i]   = f4{0.f, 0.f, 0.f, 0.f};
    for (int i = t; i < NPG * SA / 8;  i += NTHR) reinterpret_cast<f4*>(AGG)[i]  = f4{0.f, 0.f, 0.f, 0.f};
    for (int i = t; i < 112 * SW / 8;  i += NTHR) reinterpret_cast<f4*>(Wt)[i]   = f4{0.f, 0.f, 0.f, 0.f};
    if (t < NPG) s_cnt[t] = 0;
    if (t < 12)  dis16[148 + t] = 0;
    __syncthreads();

    // ---- P0b: edges -> regs + degree count; stage W (transposed, f16) + bias ----
    unsigned int epk[3];
    #pragma unroll
    for (int k = 0; k < 3; ++k) {
        const int e = t + k * NTHR;
        epk[k] = 0xffffffffu;
        if (e < EPG) {
            const int s = esrc[be + e] - bn;
            const int d = edst[be + e] - bn;
            epk[k] = (unsigned)(s | (d << 8));
            atomicAdd(&s_cnt[d], 1);
        }
    }
    for (int i = t; i < 64;   i += NTHR) Wt[(i & 15) * SW + (i >> 4)]        = (_Float16)W1[i];
    for (int i = t; i < 512;  i += NTHR) Wt[(16 + (i & 31)) * SW + (i >> 5)] = (_Float16)W2[i];
    for (int i = t; i < 2048; i += NTHR) Wt[(48 + (i & 63)) * SW + (i >> 6)] = (_Float16)W3[i];
    if (t < 16)       s_bh[t] = (_Float16)b1[t];
    else if (t < 48)  s_bh[t] = (_Float16)b2[t - 16];
    else if (t < 112) s_bh[t] = (_Float16)b3[t - 48];
    __syncthreads();

    // ---- P1: dis16 from final degrees ----
    if (t < NPG)
        dis16[t] = __builtin_bit_cast(unsigned short, (_Float16)rsqrtf((float)(s_cnt[t] + 1)));
    __syncthreads();

    // ---- P2: x -> H^T rows 0-3; scatter Ahat (CAS f16 add) + self-loop diagonal ----
    if (t < NPG) {
        const float4 xv = reinterpret_cast<const float4*>(x)[bn + t];
        HT[0 * SHT + t] = (_Float16)xv.x;
        HT[1 * SHT + t] = (_Float16)xv.y;
        HT[2 * SHT + t] = (_Float16)xv.z;
        HT[3 * SHT + t] = (_Float16)xv.w;
    }
    unsigned int* au32 = reinterpret_cast<unsigned int*>(Ahat);
    #pragma unroll
    for (int k = 0; k < 3; ++k) {
        if (epk[k] != 0xffffffffu) {
            const int s = epk[k] & 0xff;
            const int d = (epk[k] >> 8) & 0xff;
            cas_add_f16(au32 + d * (SAC / 2) + (s >> 1), s & 1, f16b(dis16[s]));
        }
    }
    if (t < NPG)
        cas_add_f16(au32 + t * (SAC / 2) + (t >> 1), t & 1, f16b(dis16[t]));
    __syncthreads();

    float* gout = out + (size_t)bn * 64;
    //    NT_AGG NT_W WROW BOFF LAST
    layer<1,     1,    0,   0,  false>(t, Ahat, HT, AGG, Wt, s_bh, dis16, gout);
    layer<1,     2,   16,  16,  false>(t, Ahat, HT, AGG, Wt, s_bh, dis16, gout);
    layer<2,     4,   48,  48,  true >(t, Ahat, HT, AGG, Wt, s_bh, dis16, gout);
}

extern "C" void kernel_launch(void* const* d_in, const int* in_sizes, int n_in,
                              void* d_out, int out_size, void* d_ws, size_t ws_size,
                              hipStream_t stream)
{
    const float* x  = (const float*)d_in[0];
    const int*   ei = (const int*)d_in[1];
    const float* W1 = (const float*)d_in[3];
    const float* b1 = (const float*)d_in[4];
    const float* W2 = (const float*)d_in[5];
    const float* b2 = (const float*)d_in[6];
    const float* W3 = (const float*)d_in[7];
    const float* b3 = (const float*)d_in[8];
    float* out = (float*)d_out;

    const int N = in_sizes[0] / 4;     // total nodes
    const int B = N / NPG;             // graphs
    const int E = in_sizes[1] / 2;     // total edges

    gcn_fused<<<B, NTHR, 0, stream>>>(x, ei, ei + E, W1, b1, W2, b2, W3, b3, out);
}

// Round 10
// 108.947 us; speedup vs baseline: 1.0327x; 1.0327x over previous
//
#include <hip/hip_runtime.h>

#define NPG 148      // nodes per graph
#define EPG 592      // edges per graph
#define NTHR 256
#define SA   36      // f16 stride of A16 rows (32 feats + 4 pad) = 72 B
#define SW   40      // f16 stride of Wt rows = 80 B
#define MT   10      // row tiles (148 -> 160)

typedef _Float16 h8 __attribute__((ext_vector_type(8)));
typedef _Float16 h4 __attribute__((ext_vector_type(4)));
typedef float    f4 __attribute__((ext_vector_type(4)));
typedef unsigned int u32;

__device__ __forceinline__ h8 bcast_pk(u32 p) {     // p = f16|f16 packed -> h8 broadcast
    uint4 q = {p, p, p, p};
    return __builtin_bit_cast(h8, q);
}

// One block = one graph (r6 skeleton + packed-f16 gather + reg-edges + degree sort).
//   G: a = dd*(dd*h[d] + sum ds*h[s])  -- all v_pk_fma_f16, degree-sorted thread->node
//   M: H' = relu(AGG @ W + b) via v_mfma_f32_16x16x32_f16 (layout verified r4-r9)
// s_meta[p] (deg-sorted): .x = nodeByteOff | disF16<<16 ; .y = csrStart | csrEnd<<16
// s_csr[e]  = srcByteOff | disF16<<16

template<int Fi, int Fo, int KC, int NTN, int MAXJ, int WROW, int BOFF, bool LAST>
__device__ __forceinline__ void layer(int t,
    _Float16* __restrict__ A16, const _Float16* __restrict__ Wt,
    const _Float16* __restrict__ s_bh, const u32* __restrict__ s_csr,
    const uint2* __restrict__ s_meta, float* __restrict__ gout)
{
    // ---- Phase G: packed-f16 gather (thread <-> sorted node) ----
    h8 a[KC];
    int off_self = 0;
    if (t < NPG) {
        const uint2 me = s_meta[t];
        off_self = (int)(me.x & 0xffffu);
        const h8 ddv = bcast_pk((me.x & 0xffff0000u) | (me.x >> 16));
        const char* base = reinterpret_cast<const char*>(A16) + off_self;
        #pragma unroll
        for (int kc = 0; kc < KC; ++kc)
            a[kc] = *reinterpret_cast<const h8*>(base + kc * 16) * ddv;
        int e = (int)(me.y & 0xffffu);
        const int e1 = (int)(me.y >> 16);
        u32 pk = (e < e1) ? s_csr[e] : 0u;
        while (e < e1) {
            const u32 pn = (e + 1 < e1) ? s_csr[e + 1] : 0u;
            const char* mb = reinterpret_cast<const char*>(A16) + (pk & 0xffffu);
            const h8 dsv = bcast_pk((pk & 0xffff0000u) | (pk >> 16));
            #pragma unroll
            for (int kc = 0; kc < KC; ++kc)
                a[kc] += *reinterpret_cast<const h8*>(mb + kc * 16) * dsv;
            pk = pn;
            ++e;
        }
        #pragma unroll
        for (int kc = 0; kc < KC; ++kc) a[kc] *= ddv;
    }
    __syncthreads();
    if (t < NPG) {
        char* base = reinterpret_cast<char*>(A16) + off_self;
        #pragma unroll
        for (int kc = 0; kc < KC; ++kc)
            *reinterpret_cast<h8*>(base + kc * 16) = a[kc];
    }
    __syncthreads();

    // ---- Phase M: MFMA. Pre-load fragments, barrier, compute+write (in-place) ----
    const int w   = t >> 6;
    const int l16 = t & 15;
    const int q   = (t >> 4) & 3;
    h8 af[MAXJ], bf[MAXJ];
    #pragma unroll
    for (int j = 0; j < MAXJ; ++j) {
        const int idx = w + 4 * j;
        if (idx < MT * NTN) {
            const int mt = idx / NTN, nt = idx % NTN;
            af[j] = *reinterpret_cast<const h8*>(&A16[(mt * 16 + l16) * SA + q * 8]);
            bf[j] = *reinterpret_cast<const h8*>(&Wt[(WROW + nt * 16 + l16) * SW + q * 8]);
        }
    }
    __syncthreads();
    #pragma unroll
    for (int j = 0; j < MAXJ; ++j) {
        const int idx = w + 4 * j;
        if (idx < MT * NTN) {
            const int mt = idx / NTN, nt = idx % NTN;
            f4 acc = {0.f, 0.f, 0.f, 0.f};
            acc = __builtin_amdgcn_mfma_f32_16x16x32_f16(af[j], bf[j], acc, 0, 0, 0);
            const int col  = nt * 16 + l16;
            const float bias = (float)s_bh[BOFF + col];
            #pragma unroll
            for (int rr = 0; rr < 4; ++rr) {
                const float v = fmaxf(acc[rr] + bias, 0.f);
                const int row = mt * 16 + q * 4 + rr;
                if (LAST) {
                    if (row < NPG) gout[row * 64 + col] = v;
                } else {
                    A16[row * SA + col] = (_Float16)v;
                }
            }
        }
    }
    if (!LAST) __syncthreads();
}

__global__ __launch_bounds__(256, 6)
void gcn_fused(const float* __restrict__ x,
               const int* __restrict__ esrc, const int* __restrict__ edst,
               const float* __restrict__ W1, const float* __restrict__ b1,
               const float* __restrict__ W2, const float* __restrict__ b2,
               const float* __restrict__ W3, const float* __restrict__ b3,
               float* __restrict__ out)
{
    __shared__ __align__(16) _Float16 A16[160 * SA];     // 11520 B node features (in-place)
    __shared__ __align__(16) _Float16 Wt[112 * SW];      //  8960 B W1t|W2t|W3t (K-padded)
    __shared__ _Float16 s_bh[112];
    __shared__ u32 s_csr[EPG];                           //  2368 B
    __shared__ unsigned short s_row[152];
    __shared__ unsigned short s_dis[NPG];
    __shared__ uint2 s_meta[NPG];                        //  1184 B (deg-sorted)
    __shared__ int s_cnt[NPG], s_cnt2[NPG];
    __shared__ int s_hist[64], s_boff[64], s_bcnt[64];
    // total ~26.8 KB -> 6 blocks/CU

    const int t  = threadIdx.x;
    const int g  = blockIdx.x;
    const int be = g * EPG;
    const int bn = g * NPG;

    // ---- P0a: zero A16/Wt (K/M pads must be 0) + all counters ----
    for (int i = t; i < 160 * SA / 8; i += NTHR)
        reinterpret_cast<f4*>(A16)[i] = f4{0.f, 0.f, 0.f, 0.f};
    for (int i = t; i < 112 * SW / 8; i += NTHR)
        reinterpret_cast<f4*>(Wt)[i] = f4{0.f, 0.f, 0.f, 0.f};
    if (t < NPG) { s_cnt[t] = 0; s_cnt2[t] = 0; }
    if (t < 64)  { s_hist[t] = 0; s_bcnt[t] = 0; }
    __syncthreads();

    // ---- P0b: edges -> regs + degree count; stage W^T f16, bias, x -> A16 ----
    u32 epk[3];
    #pragma unroll
    for (int k = 0; k < 3; ++k) {
        const int e = t + k * NTHR;
        epk[k] = 0xffffffffu;
        if (e < EPG) {
            const int s = esrc[be + e] - bn;
            const int d = edst[be + e] - bn;
            epk[k] = (u32)(s | (d << 8));
            atomicAdd(&s_cnt[d], 1);
        }
    }
    for (int i = t; i < 64;   i += NTHR) Wt[(i & 15) * SW + (i >> 4)]        = (_Float16)W1[i];
    for (int i = t; i < 512;  i += NTHR) Wt[(16 + (i & 31)) * SW + (i >> 5)] = (_Float16)W2[i];
    for (int i = t; i < 2048; i += NTHR) Wt[(48 + (i & 63)) * SW + (i >> 6)] = (_Float16)W3[i];
    if (t < 16)       s_bh[t] = (_Float16)b1[t];
    else if (t < 48)  s_bh[t] = (_Float16)b2[t - 16];
    else if (t < 112) s_bh[t] = (_Float16)b3[t - 48];
    if (t < NPG) {
        const float4 xv = reinterpret_cast<const float4*>(x)[bn + t];
        h4 p; p[0] = (_Float16)xv.x; p[1] = (_Float16)xv.y; p[2] = (_Float16)xv.z; p[3] = (_Float16)xv.w;
        *reinterpret_cast<h4*>(&A16[t * SA]) = p;
    }
    __syncthreads();

    // ---- P1: dis (f16) + degree histogram ----
    if (t < NPG) {
        const int deg = s_cnt[t];
        s_dis[t] = __builtin_bit_cast(unsigned short, (_Float16)rsqrtf((float)(deg + 1)));
        atomicAdd(&s_hist[min(deg, 63)], 1);
    }
    __syncthreads();

    // ---- P2: wave0: node-count scan -> s_row ; wave1: degree-bucket scan -> s_boff ----
    if (t < 64) {
        const int lane = t;
        int v0 = s_cnt[lane];
        int v1 = s_cnt[64 + lane];
        int v2 = (128 + lane < NPG) ? s_cnt[128 + lane] : 0;
        #pragma unroll
        for (int off = 1; off < 64; off <<= 1) {
            const int u0 = __shfl_up(v0, off);
            const int u1 = __shfl_up(v1, off);
            const int u2 = __shfl_up(v2, off);
            if (lane >= off) { v0 += u0; v1 += u1; v2 += u2; }
        }
        const int t0 = __shfl(v0, 63);
        const int t1 = __shfl(v1, 63);
        v1 += t0;
        v2 += t0 + t1;
        if (lane == 0) s_row[0] = 0;
        s_row[1 + lane]  = (unsigned short)v0;
        s_row[65 + lane] = (unsigned short)v1;
        if (128 + lane < NPG) s_row[129 + lane] = (unsigned short)v2;
    } else if (t < 128) {
        const int lane = t - 64;
        const int orig = s_hist[lane];
        int v = orig;
        #pragma unroll
        for (int off = 1; off < 64; off <<= 1) {
            const int u = __shfl_up(v, off);
            if (lane >= off) v += u;
        }
        s_boff[lane] = v - orig;     // exclusive prefix
    }
    __syncthreads();

    // ---- P3: scatter packed CSR + degree-sorted meta ----
    #pragma unroll
    for (int k = 0; k < 3; ++k) {
        if (epk[k] != 0xffffffffu) {
            const int s = epk[k] & 0xff;
            const int d = (epk[k] >> 8) & 0xff;
            const int pos = (int)s_row[d] + atomicAdd(&s_cnt2[d], 1);
            s_csr[pos] = (u32)(s * (SA * 2)) | ((u32)s_dis[s] << 16);
        }
    }
    if (t < NPG) {
        const int deg = s_cnt[t];
        const int b   = min(deg, 63);
        const int p   = s_boff[b] + atomicAdd(&s_bcnt[b], 1);
        s_meta[p] = make_uint2((u32)(t * (SA * 2)) | ((u32)s_dis[t] << 16),
                               (u32)s_row[t] | ((u32)s_row[t + 1] << 16));
    }
    __syncthreads();

    float* gout = out + (size_t)bn * 64;
    //     Fi  Fo  KC NTN MAXJ WROW BOFF LAST
    layer< 4, 16,  1,  1,   3,    0,   0, false>(t, A16, Wt, s_bh, s_csr, s_meta, gout);
    layer<16, 32,  2,  2,   5,   16,  16, false>(t, A16, Wt, s_bh, s_csr, s_meta, gout);
    layer<32, 64,  4,  4,  10,   48,  48, true >(t, A16, Wt, s_bh, s_csr, s_meta, gout);
}

extern "C" void kernel_launch(void* const* d_in, const int* in_sizes, int n_in,
                              void* d_out, int out_size, void* d_ws, size_t ws_size,
                              hipStream_t stream)
{
    const float* x  = (const float*)d_in[0];
    const int*   ei = (const int*)d_in[1];
    const float* W1 = (const float*)d_in[3];
    const float* b1 = (const float*)d_in[4];
    const float* W2 = (const float*)d_in[5];
    const float* b2 = (const float*)d_in[6];
    const float* W3 = (const float*)d_in[7];
    const float* b3 = (const float*)d_in[8];
    float* out = (float*)d_out;

    const int N = in_sizes[0] / 4;     // total nodes
    const int B = N / NPG;             // graphs
    const int E = in_sizes[1] / 2;     // total edges

    gcn_fused<<<B, NTHR, 0, stream>>>(x, ei, ei + E, W1, b1, W2, b2, W3, b3, out);
}

// Round 11
// 108.257 us; speedup vs baseline: 1.0393x; 1.0064x over previous
//
#include <hip/hip_runtime.h>

#define NPG 148      // nodes per graph
#define EPG 592      // edges per graph
#define NTHR 512
#define GPB  2       // graphs per block
#define SA   36      // f16 stride of A16 rows (32 feats + 4 pad) = 72 B
#define SW   40      // f16 stride of Wt rows = 80 B
#define MT   10      // row tiles (148 -> 160)

typedef _Float16 h8 __attribute__((ext_vector_type(8)));
typedef _Float16 h4 __attribute__((ext_vector_type(4)));
typedef float    f4 __attribute__((ext_vector_type(4)));
typedef unsigned int u32;

__device__ __forceinline__ float f16b(unsigned short u) {
    return (float)__builtin_bit_cast(_Float16, u);
}

// One block = TWO graphs (halves: threads 0-255 graph A, 256-511 graph B).
// Per layer (r6-verified math):
//   G: thread tl<148 <-> node; f32 acc, fma_mix over f16 LDS reads, pipelined CSR walk
//   M: H' = relu(AGG @ W + b) via v_mfma_f32_16x16x32_f16 (4 waves per graph-half)
// s_csr[e] = srcByteOff | disF16<<16

template<int Fi, int Fo, int KC, int NTN, int MAXJ, int WROW, int BOFF, bool LAST>
__device__ __forceinline__ void layer(int tl,
    _Float16* __restrict__ A16, const _Float16* __restrict__ Wt,
    const _Float16* __restrict__ s_bh, const u32* __restrict__ s_csr,
    const unsigned short* __restrict__ s_row, const unsigned short* __restrict__ s_dis,
    float* __restrict__ gout)
{
    // ---- Phase G: per-thread node, KC-wide f32 accumulate, pipelined csr reads ----
    float a[KC][8];
    if (tl < NPG) {
        const float dd = f16b(s_dis[tl]);
        const char* selfb = reinterpret_cast<const char*>(A16) + tl * (SA * 2);
        #pragma unroll
        for (int kc = 0; kc < KC; ++kc) {
            const h8 hv = *reinterpret_cast<const h8*>(selfb + kc * 16);
            #pragma unroll
            for (int u = 0; u < 8; ++u) a[kc][u] = dd * (float)hv[u];
        }
        int e  = s_row[tl];
        const int e1 = s_row[tl + 1];
        u32 pk = (e < e1) ? s_csr[e] : 0u;
        while (e < e1) {
            const u32 pn = (e + 1 < e1) ? s_csr[e + 1] : 0u;
            const char* mb = reinterpret_cast<const char*>(A16) + (pk & 0xffffu);
            const float ds = f16b((unsigned short)(pk >> 16));
            #pragma unroll
            for (int kc = 0; kc < KC; ++kc) {
                const h8 m = *reinterpret_cast<const h8*>(mb + kc * 16);
                #pragma unroll
                for (int u = 0; u < 8; ++u) a[kc][u] = fmaf((float)m[u], ds, a[kc][u]);
            }
            pk = pn;
            ++e;
        }
        #pragma unroll
        for (int kc = 0; kc < KC; ++kc)
            #pragma unroll
            for (int u = 0; u < 8; ++u) a[kc][u] *= dd;
    }
    __syncthreads();
    if (tl < NPG) {
        char* selfb = reinterpret_cast<char*>(A16) + tl * (SA * 2);
        #pragma unroll
        for (int kc = 0; kc < KC; ++kc) {
            h8 pv;
            #pragma unroll
            for (int u = 0; u < 8; ++u) pv[u] = (_Float16)a[kc][u];
            *reinterpret_cast<h8*>(selfb + kc * 16) = pv;
        }
    }
    __syncthreads();

    // ---- Phase M: MFMA. Pre-load fragments, barrier, compute+write (in-place) ----
    const int w   = tl >> 6;          // wave within this graph-half: 0..3
    const int l16 = tl & 15;
    const int q   = (tl >> 4) & 3;
    h8 af[MAXJ], bf[MAXJ];
    #pragma unroll
    for (int j = 0; j < MAXJ; ++j) {
        const int idx = w + 4 * j;
        if (idx < MT * NTN) {
            const int mt = idx / NTN, nt = idx % NTN;
            af[j] = *reinterpret_cast<const h8*>(&A16[(mt * 16 + l16) * SA + q * 8]);
            bf[j] = *reinterpret_cast<const h8*>(&Wt[(WROW + nt * 16 + l16) * SW + q * 8]);
        }
    }
    __syncthreads();
    #pragma unroll
    for (int j = 0; j < MAXJ; ++j) {
        const int idx = w + 4 * j;
        if (idx < MT * NTN) {
            const int mt = idx / NTN, nt = idx % NTN;
            f4 acc = {0.f, 0.f, 0.f, 0.f};
            acc = __builtin_amdgcn_mfma_f32_16x16x32_f16(af[j], bf[j], acc, 0, 0, 0);
            const int col  = nt * 16 + l16;
            const float bias = (float)s_bh[BOFF + col];
            #pragma unroll
            for (int rr = 0; rr < 4; ++rr) {
                const float v = fmaxf(acc[rr] + bias, 0.f);
                const int row = mt * 16 + q * 4 + rr;
                if (LAST) {
                    if (row < NPG) gout[row * 64 + col] = v;
                } else {
                    A16[row * SA + col] = (_Float16)v;
                }
            }
        }
    }
    if (!LAST) __syncthreads();
}

__global__ __launch_bounds__(NTHR, 8)
void gcn_fused(const float* __restrict__ x,
               const int* __restrict__ esrc, const int* __restrict__ edst,
               const float* __restrict__ W1, const float* __restrict__ b1,
               const float* __restrict__ W2, const float* __restrict__ b2,
               const float* __restrict__ W3, const float* __restrict__ b3,
               float* __restrict__ out)
{
    __shared__ __align__(16) _Float16 A16[GPB][160 * SA];  // 23040 B
    __shared__ __align__(16) _Float16 Wt[112 * SW];        //  8960 B (shared by both graphs)
    __shared__ _Float16 s_bh[112];                         //   224 B
    __shared__ u32 s_csr[GPB][EPG];                        //  4736 B
    __shared__ unsigned short s_row[GPB][152];             //   608 B
    __shared__ unsigned short s_dis[GPB][NPG];             //   592 B
    __shared__ int s_cnt[GPB][NPG], s_cnt2[GPB][NPG];      //  2368 B
    // total 40528 B -> 4 blocks/CU (32 waves/CU)

    const int t  = threadIdx.x;
    const int gl = t >> 8;                 // local graph half 0/1
    const int tl = t & 255;
    const int g  = blockIdx.x * GPB + gl;  // this half's graph
    const int be = g * EPG;
    const int bn = g * NPG;

    // ---- P0a: zero A16/Wt (K/M pads must be 0) + counters ----
    for (int i = t; i < GPB * 160 * SA / 8; i += NTHR)
        reinterpret_cast<f4*>(&A16[0][0])[i] = f4{0.f, 0.f, 0.f, 0.f};
    for (int i = t; i < 112 * SW / 8; i += NTHR)
        reinterpret_cast<f4*>(Wt)[i] = f4{0.f, 0.f, 0.f, 0.f};
    if (tl < NPG) { s_cnt[gl][tl] = 0; s_cnt2[gl][tl] = 0; }
    __syncthreads();

    // ---- P0b: edges -> regs + degree; stage W^T f16 (once), bias, x -> A16 ----
    u32 epk[3];
    #pragma unroll
    for (int k = 0; k < 3; ++k) {
        const int e = tl + k * 256;
        epk[k] = 0xffffffffu;
        if (e < EPG) {
            const int s = esrc[be + e] - bn;
            const int d = edst[be + e] - bn;
            epk[k] = (u32)(s | (d << 8));
            atomicAdd(&s_cnt[gl][d], 1);
        }
    }
    for (int i = t; i < 64;   i += NTHR) Wt[(i & 15) * SW + (i >> 4)]        = (_Float16)W1[i];
    for (int i = t; i < 512;  i += NTHR) Wt[(16 + (i & 31)) * SW + (i >> 5)] = (_Float16)W2[i];
    for (int i = t; i < 2048; i += NTHR) Wt[(48 + (i & 63)) * SW + (i >> 6)] = (_Float16)W3[i];
    if (t < 16)       s_bh[t] = (_Float16)b1[t];
    else if (t < 48)  s_bh[t] = (_Float16)b2[t - 16];
    else if (t < 112) s_bh[t] = (_Float16)b3[t - 48];
    if (tl < NPG) {
        const float4 xv = reinterpret_cast<const float4*>(x)[bn + tl];
        h4 p; p[0] = (_Float16)xv.x; p[1] = (_Float16)xv.y; p[2] = (_Float16)xv.z; p[3] = (_Float16)xv.w;
        *reinterpret_cast<h4*>(&A16[gl][tl * SA]) = p;
    }
    __syncthreads();

    // ---- P1+P2: dis (f16); wave-scan per half (wave 0 -> graph0, wave 4 -> graph1) ----
    if (tl < NPG)
        s_dis[gl][tl] = __builtin_bit_cast(unsigned short,
                                           (_Float16)rsqrtf((float)(s_cnt[gl][tl] + 1)));
    if (tl < 64) {
        const int lane = tl;
        int v0 = s_cnt[gl][lane];
        int v1 = s_cnt[gl][64 + lane];
        int v2 = (128 + lane < NPG) ? s_cnt[gl][128 + lane] : 0;
        #pragma unroll
        for (int off = 1; off < 64; off <<= 1) {
            const int u0 = __shfl_up(v0, off);
            const int u1 = __shfl_up(v1, off);
            const int u2 = __shfl_up(v2, off);
            if (lane >= off) { v0 += u0; v1 += u1; v2 += u2; }
        }
        const int t0 = __shfl(v0, 63);
        const int t1 = __shfl(v1, 63);
        v1 += t0;
        v2 += t0 + t1;
        if (lane == 0) s_row[gl][0] = 0;
        s_row[gl][1 + lane]  = (unsigned short)v0;
        s_row[gl][65 + lane] = (unsigned short)v1;
        if (128 + lane < NPG) s_row[gl][129 + lane] = (unsigned short)v2;
    }
    __syncthreads();

    // ---- P3: scatter packed CSR (srcByteOff | disF16<<16) ----
    #pragma unroll
    for (int k = 0; k < 3; ++k) {
        if (epk[k] != 0xffffffffu) {
            const int s = epk[k] & 0xff;
            const int d = (epk[k] >> 8) & 0xff;
            const int pos = (int)s_row[gl][d] + atomicAdd(&s_cnt2[gl][d], 1);
            s_csr[gl][pos] = (u32)(s * (SA * 2)) | ((u32)s_dis[gl][s] << 16);
        }
    }
    __syncthreads();

    float* gout = out + (size_t)bn * 64;
    //     Fi  Fo  KC NTN MAXJ WROW BOFF LAST
    layer< 4, 16,  1,  1,   3,    0,   0, false>(tl, A16[gl], Wt, s_bh, s_csr[gl], s_row[gl], s_dis[gl], gout);
    layer<16, 32,  2,  2,   5,   16,  16, false>(tl, A16[gl], Wt, s_bh, s_csr[gl], s_row[gl], s_dis[gl], gout);
    layer<32, 64,  4,  4,  10,   48,  48, true >(tl, A16[gl], Wt, s_bh, s_csr[gl], s_row[gl], s_dis[gl], gout);
}

extern "C" void kernel_launch(void* const* d_in, const int* in_sizes, int n_in,
                              void* d_out, int out_size, void* d_ws, size_t ws_size,
                              hipStream_t stream)
{
    const float* x  = (const float*)d_in[0];
    const int*   ei = (const int*)d_in[1];
    const float* W1 = (const float*)d_in[3];
    const float* b1 = (const float*)d_in[4];
    const float* W2 = (const float*)d_in[5];
    const float* b2 = (const float*)d_in[6];
    const float* W3 = (const float*)d_in[7];
    const float* b3 = (const float*)d_in[8];
    float* out = (float*)d_out;

    const int N = in_sizes[0] / 4;     // total nodes
    const int B = N / NPG;             // graphs
    const int E = in_sizes[1] / 2;     // total edges

    gcn_fused<<<B / GPB, NTHR, 0, stream>>>(x, ei, ei + E, W1, b1, W2, b2, W3, b3, out);
}